// Round 1
// baseline (1834.078 us; speedup 1.0000x reference)
//
#include <hip/hip_runtime.h>
#include <hip/hip_bf16.h>

// ---------------------------------------------------------------------------
// Full fp32 implementation of the mv3Dunet_down_text_cmsa forward pass.
// B=32, spatial 4x7x7 (196), conv ch 320->128->128, text 45 ch, feat 173 ch.
// ---------------------------------------------------------------------------

#define DEVINL __device__ __forceinline__

// ---------------- transpose (w[O,I] -> wt[I,O]) ----------------
__global__ void k_transpose(const float* __restrict__ w, float* __restrict__ wt,
                            int O, int I) {
    int i = blockIdx.x;
    for (int o = threadIdx.x; o < O; o += blockDim.x)
        wt[i * O + o] = w[o * I + i];
}

// ---------------- 3x3x3 'same' conv, NCDHW, bias omitted (BN cancels it) ----
#define CONV_OTILE 8
#define CONV_CCHUNK 16
// padded x tile: [16][6][9][12] floats ; weights [16][8][28]
__global__ __launch_bounds__(256) void k_conv3d(
    const float* __restrict__ x, const float* __restrict__ w,
    float* __restrict__ y, int IC, int OC) {
    __shared__ float xs[CONV_CCHUNK * 648];
    __shared__ float wsh[CONV_CCHUNK * CONV_OTILE * 28];
    int b = blockIdx.y;
    int o0 = blockIdx.x * CONV_OTILE;
    int tid = threadIdx.x;

    for (int i = tid; i < CONV_CCHUNK * 648; i += 256) xs[i] = 0.f;

    int ol = tid / 28;
    int dh = tid - ol * 28;
    int d = dh / 7, h = dh - (dh / 7) * 7;
    bool active = tid < 224;
    float acc[7];
#pragma unroll
    for (int i = 0; i < 7; ++i) acc[i] = 0.f;

    for (int c0 = 0; c0 < IC; c0 += CONV_CCHUNK) {
        __syncthreads();
        for (int i = tid; i < CONV_CCHUNK * 196; i += 256) {
            int cc = i / 196, ss = i - cc * 196;
            int dd = ss / 49; int rr = ss - dd * 49;
            int hh = rr / 7;  int ww = rr - hh * 7;
            xs[cc * 648 + (dd + 1) * 108 + (hh + 1) * 12 + (ww + 1)] =
                x[(size_t)(b * IC + c0 + cc) * 196 + ss];
        }
        for (int i = tid; i < CONV_CCHUNK * CONV_OTILE * 27; i += 256) {
            int cc = i / (CONV_OTILE * 27);
            int r = i - cc * CONV_OTILE * 27;
            int oo = r / 27; int k = r - oo * 27;
            wsh[(cc * CONV_OTILE + oo) * 28 + k] =
                w[(size_t)((o0 + oo) * IC + c0 + cc) * 27 + k];
        }
        __syncthreads();
        if (active) {
            for (int cc = 0; cc < CONV_CCHUNK; ++cc) {
                const float* wp = &wsh[(cc * CONV_OTILE + ol) * 28];
                float wr[27];
#pragma unroll
                for (int k = 0; k < 27; ++k) wr[k] = wp[k];
                const float* xb = &xs[cc * 648 + d * 108 + h * 12];
#pragma unroll
                for (int kd = 0; kd < 3; ++kd) {
#pragma unroll
                    for (int kh = 0; kh < 3; ++kh) {
                        const float* row = xb + kd * 108 + kh * 12;
                        float r0 = row[0], r1 = row[1], r2 = row[2], r3 = row[3];
                        float r4 = row[4], r5 = row[5], r6 = row[6], r7 = row[7];
                        float r8 = row[8];
                        float w0 = wr[kd * 9 + kh * 3 + 0];
                        float w1 = wr[kd * 9 + kh * 3 + 1];
                        float w2 = wr[kd * 9 + kh * 3 + 2];
                        acc[0] += r0 * w0 + r1 * w1 + r2 * w2;
                        acc[1] += r1 * w0 + r2 * w1 + r3 * w2;
                        acc[2] += r2 * w0 + r3 * w1 + r4 * w2;
                        acc[3] += r3 * w0 + r4 * w1 + r5 * w2;
                        acc[4] += r4 * w0 + r5 * w1 + r6 * w2;
                        acc[5] += r5 * w0 + r6 * w1 + r7 * w2;
                        acc[6] += r6 * w0 + r7 * w1 + r8 * w2;
                    }
                }
            }
        }
    }
    if (active) {
        int o = o0 + ol;
        float* yp = &y[(size_t)(b * OC + o) * 196 + d * 49 + h * 7];
#pragma unroll
        for (int i = 0; i < 7; ++i) yp[i] = acc[i];
    }
}

// ---------------- BN (training mode, axes 0,2,3,4) ----------------
__global__ void k_bn_stats(const float* __restrict__ y, float* __restrict__ stats,
                           int C) {
    int ch = blockIdx.x; int tid = threadIdx.x;
    float s = 0.f, s2 = 0.f;
    for (int b = 0; b < 32; ++b) {
        const float* p = &y[(size_t)(b * C + ch) * 196];
        for (int i = tid; i < 196; i += 256) { float v = p[i]; s += v; s2 += v * v; }
    }
    __shared__ float r1[4], r2[4];
    for (int sh = 32; sh; sh >>= 1) { s += __shfl_xor(s, sh); s2 += __shfl_xor(s2, sh); }
    if ((tid & 63) == 0) { r1[tid >> 6] = s; r2[tid >> 6] = s2; }
    __syncthreads();
    if (tid == 0) {
        float S = r1[0] + r1[1] + r1[2] + r1[3];
        float S2 = r2[0] + r2[1] + r2[2] + r2[3];
        float m = S / 6272.f;
        float v = S2 / 6272.f - m * m;
        stats[2 * ch] = m;
        stats[2 * ch + 1] = rsqrtf(v + 1e-5f);
    }
}

__global__ void k_bn_apply_relu(float* __restrict__ y, const float* __restrict__ stats,
                                const float* __restrict__ g, const float* __restrict__ be,
                                int C) {
    int idx = blockIdx.x;           // b*C + ch
    int ch = idx % C;
    int s = threadIdx.x;
    if (s < 196) {
        float m = stats[2 * ch], r = stats[2 * ch + 1];
        float v = y[(size_t)idx * 196 + s];
        y[(size_t)idx * 196 + s] = fmaxf((v - m) * r * g[ch] + be[ch], 0.f);
    }
}

// ---------------- catnum: Linear(A->196) + BN over batch + SiLU -------------
__global__ void k_catnum(const float* __restrict__ inp, int A,
                         const float* __restrict__ w, const float* __restrict__ bias,
                         const float* __restrict__ g, const float* __restrict__ be,
                         float* __restrict__ outv) {
    int j = blockIdx.x;             // feature 0..195
    int lane = threadIdx.x;         // 64 threads, 32 active
    float v = 0.f;
    if (lane < 32) {
        v = bias[j];
        for (int k = 0; k < A; ++k) v += inp[lane * A + k] * w[j * A + k];
    }
    float s = (lane < 32) ? v : 0.f;
    float s2 = (lane < 32) ? v * v : 0.f;
    for (int m = 16; m; m >>= 1) { s += __shfl_xor(s, m, 32); s2 += __shfl_xor(s2, m, 32); }
    if (lane < 32) {
        float mean = s / 32.f;
        float var = s2 / 32.f - mean * mean;
        float rstd = rsqrtf(var + 1e-5f);
        float t = (v - mean) * rstd * g[j] + be[j];
        t = t / (1.f + expf(-t));   // SiLU
        outv[lane * 196 + j] = t;
    }
}

__global__ void k_textbuild(const float* __restrict__ toh, const float* __restrict__ tnm,
                            float* __restrict__ text) {
    int idx = blockIdx.x;           // b*45+c
    int b = idx / 45, c = idx - b * 45;
    int s = threadIdx.x;
    if (s < 196) text[(size_t)idx * 196 + s] = (c < 30) ? toh[b * 196 + s] : tnm[b * 196 + s];
}

// ---------------- GCN ----------------
__global__ void k_gcn_dist(const float* __restrict__ f, float* __restrict__ dist, int C) {
    int idx = blockIdx.x;           // b*C+i
    int b = idx / C;
    __shared__ float fi[196];
    int tid = threadIdx.x;
    for (int n = tid; n < 196; n += blockDim.x) fi[n] = f[(size_t)idx * 196 + n];
    __syncthreads();
    if (tid < C) {
        const float* fj = &f[(size_t)(b * C + tid) * 196];
        float s = 0.f;
        for (int n = 0; n < 196; ++n) s += fabsf(fi[n] - fj[n]);
        dist[(size_t)idx * C + tid] = expf(-s);
    }
}

__global__ void k_gcn_spmm(const float* __restrict__ dist, const float* __restrict__ f,
                           float* __restrict__ tmp, int C) {
    int idx = blockIdx.x;           // b*C+i
    int b = idx / C;
    __shared__ float ds[128];
    for (int j = threadIdx.x; j < C; j += 256) ds[j] = dist[(size_t)idx * C + j];
    __syncthreads();
    int n = threadIdx.x;
    if (n < 196) {
        float acc = 0.f;
        for (int j = 0; j < C; ++j) acc += ds[j] * f[(size_t)(b * C + j) * 196 + n];
        tmp[(size_t)idx * 196 + n] = acc;
    }
}

__global__ void k_gcn_fin(const float* __restrict__ tmp, const float* __restrict__ wt,
                          const float* __restrict__ bias, const float* __restrict__ f,
                          float* __restrict__ out) {
    int row = blockIdx.x;
    __shared__ float ts[196];
    for (int n = threadIdx.x; n < 196; n += 256) ts[n] = tmp[(size_t)row * 196 + n];
    __syncthreads();
    int k = threadIdx.x;
    if (k < 196) {
        float acc = bias[k];
        for (int n = 0; n < 196; ++n) acc += ts[n] * wt[n * 196 + k];
        out[(size_t)row * 196 + k] = fmaxf(acc, 0.f) + f[(size_t)row * 196 + k];
    }
}

// ---------------- LayerNorm over last dim (196), eps 1e-6 ----------------
__global__ void k_ln(const float* __restrict__ x, const float* __restrict__ g,
                     const float* __restrict__ be, float* __restrict__ out) {
    int row = blockIdx.x;
    int lane = threadIdx.x;         // 64
    float v[4]; float s = 0.f, s2 = 0.f;
#pragma unroll
    for (int k = 0; k < 4; ++k) {
        int n = lane + 64 * k;
        v[k] = (n < 196) ? x[(size_t)row * 196 + n] : 0.f;
        s += v[k]; s2 += v[k] * v[k];
    }
    for (int m = 32; m; m >>= 1) { s += __shfl_xor(s, m); s2 += __shfl_xor(s2, m); }
    float mean = s / 196.f;
    float var = s2 / 196.f - mean * mean;
    float rstd = rsqrtf(var + 1e-6f);
#pragma unroll
    for (int k = 0; k < 4; ++k) {
        int n = lane + 64 * k;
        if (n < 196) out[(size_t)row * 196 + n] = (v[k] - mean) * rstd * g[n] + be[n];
    }
}

// ---------------- row GEMV: out = act(x @ wt + b) ----------------
template <int RELU>
__global__ void k_lin(const float* __restrict__ x, const float* __restrict__ wt,
                      const float* __restrict__ bias, float* __restrict__ out) {
    int row = blockIdx.x;
    __shared__ float xs[196];
    for (int n = threadIdx.x; n < 196; n += 256) xs[n] = x[(size_t)row * 196 + n];
    __syncthreads();
    int o = threadIdx.x;
    if (o < 196) {
        float acc = bias[o];
        for (int n = 0; n < 196; ++n) acc += xs[n] * wt[n * 196 + o];
        out[(size_t)row * 196 + o] = RELU ? fmaxf(acc, 0.f) : acc;
    }
}

// out = x1@w1t + b1 + x2@w2t + b2 + res
__global__ void k_fuse2(const float* __restrict__ x1, const float* __restrict__ w1t,
                        const float* __restrict__ b1, const float* __restrict__ x2,
                        const float* __restrict__ w2t, const float* __restrict__ b2,
                        const float* __restrict__ res, float* __restrict__ out) {
    int row = blockIdx.x;
    __shared__ float s1[196], s2[196];
    for (int n = threadIdx.x; n < 196; n += 256) {
        s1[n] = x1[(size_t)row * 196 + n];
        s2[n] = x2[(size_t)row * 196 + n];
    }
    __syncthreads();
    int o = threadIdx.x;
    if (o < 196) {
        float acc = b1[o] + b2[o] + res[(size_t)row * 196 + o];
        for (int n = 0; n < 196; ++n)
            acc += s1[n] * w1t[n * 196 + o] + s2[n] * w2t[n * 196 + o];
        out[(size_t)row * 196 + o] = acc;
    }
}

// ---------------- attention: A = softmax(q @ k^T) ----------------
__global__ void k_att(const float* __restrict__ q, const float* __restrict__ k,
                      float* __restrict__ A, int R2) {
    int i = blockIdx.x, b = blockIdx.y, R1 = gridDim.x;
    __shared__ float qs[196];
    __shared__ float red[2];
    int tid = threadIdx.x;
    for (int n = tid; n < 196; n += blockDim.x) qs[n] = q[(size_t)(b * R1 + i) * 196 + n];
    __syncthreads();
    float sc = -1e30f;
    if (tid < R2) {
        const float* kr = &k[(size_t)(b * R2 + tid) * 196];
        float acc = 0.f;
        for (int n = 0; n < 196; ++n) acc += qs[n] * kr[n];
        sc = acc;
    }
    float m = sc;
    for (int sh = 32; sh; sh >>= 1) m = fmaxf(m, __shfl_xor(m, sh));
    int nw = blockDim.x >> 6;
    if (nw > 1) {
        if ((tid & 63) == 0) red[tid >> 6] = m;
        __syncthreads();
        m = fmaxf(red[0], red[1]);
        __syncthreads();
    }
    float e = (tid < R2) ? expf(sc - m) : 0.f;
    float s = e;
    for (int sh = 32; sh; sh >>= 1) s += __shfl_xor(s, sh);
    if (nw > 1) {
        if ((tid & 63) == 0) red[tid >> 6] = s;
        __syncthreads();
        s = red[0] + red[1];
    }
    if (tid < R2) A[(size_t)(b * R1 + i) * R2 + tid] = e / s;
}

// out[b,i,:] = sum_j A[b,i,j] * v[b,j,:]
__global__ void k_attv(const float* __restrict__ A, const float* __restrict__ v,
                       float* __restrict__ out, int R2) {
    int i = blockIdx.x, b = blockIdx.y, R1 = gridDim.x;
    __shared__ float as[128];
    int tid = threadIdx.x;
    for (int j = tid; j < R2; j += 256) as[j] = A[(size_t)(b * R1 + i) * R2 + j];
    __syncthreads();
    if (tid < 196) {
        float acc = 0.f;
        for (int j = 0; j < R2; ++j) acc += as[j] * v[(size_t)(b * R2 + j) * 196 + tid];
        out[(size_t)(b * R1 + i) * 196 + tid] = acc;
    }
}

// ---------------- feat = concat(ci + c5f, ct + txf) ----------------
__global__ void k_featbuild(const float* __restrict__ ci, const float* __restrict__ c5f,
                            const float* __restrict__ ct, const float* __restrict__ txf,
                            float* __restrict__ feat) {
    int idx = blockIdx.x;           // b*173+c
    int b = idx / 173, c = idx - b * 173;
    int s = threadIdx.x;
    if (s < 196) {
        float v;
        if (c < 128)
            v = ci[(size_t)(b * 128 + c) * 196 + s] + c5f[(size_t)(b * 128 + c) * 196 + s];
        else
            v = ct[(size_t)(b * 45 + c - 128) * 196 + s] + txf[(size_t)(b * 45 + c - 128) * 196 + s];
        feat[(size_t)idx * 196 + s] = v;
    }
}

// ---------------- 1x1x1 conv (channel mix), relu, optional residual --------
template <int RES>
__global__ void k_conv1x1(const float* __restrict__ x, const float* __restrict__ w,
                          const float* __restrict__ bias, const float* __restrict__ res,
                          float* __restrict__ out, int C) {
    int o = blockIdx.x, b = blockIdx.y;
    __shared__ float wsm[173];
    for (int c = threadIdx.x; c < C; c += 256) wsm[c] = w[o * C + c];
    __syncthreads();
    int s = threadIdx.x;
    if (s < 196) {
        float acc = bias[o];
        for (int c = 0; c < C; ++c) acc += wsm[c] * x[(size_t)(b * C + c) * 196 + s];
        acc = fmaxf(acc, 0.f);
        if (RES) acc += res[(size_t)(b * C + o) * 196 + s];
        out[(size_t)(b * C + o) * 196 + s] = acc;
    }
}

// ---------------- CMSA attention over positions ----------------
__global__ void k_cmsa_att(const float* __restrict__ q, float* __restrict__ A) {
    int i = blockIdx.x, b = blockIdx.y;   // i in [0,196)
    __shared__ float col[173];
    __shared__ float red[4];
    int tid = threadIdx.x;
    for (int c = tid; c < 173; c += 256) col[c] = q[(size_t)(b * 173 + c) * 196 + i];
    __syncthreads();
    float sc = -1e30f;
    if (tid < 196) {
        float acc = 0.f;
        for (int c = 0; c < 173; ++c) acc += col[c] * q[(size_t)(b * 173 + c) * 196 + tid];
        sc = acc;
    }
    float m = sc;
    for (int sh = 32; sh; sh >>= 1) m = fmaxf(m, __shfl_xor(m, sh));
    if ((tid & 63) == 0) red[tid >> 6] = m;
    __syncthreads();
    m = fmaxf(fmaxf(red[0], red[1]), fmaxf(red[2], red[3]));
    __syncthreads();
    float e = (tid < 196) ? expf(sc - m) : 0.f;
    float s = e;
    for (int sh = 32; sh; sh >>= 1) s += __shfl_xor(s, sh);
    if ((tid & 63) == 0) red[tid >> 6] = s;
    __syncthreads();
    s = red[0] + red[1] + red[2] + red[3];
    if (tid < 196) A[(size_t)(b * 196 + i) * 196 + tid] = e / s;
}

__global__ void k_cmsa_apply(const float* __restrict__ A, const float* __restrict__ q,
                             float* __restrict__ fea) {
    int c = blockIdx.x, b = blockIdx.y;
    __shared__ float qs[196];
    int tid = threadIdx.x;
    for (int n = tid; n < 196; n += 256) qs[n] = q[(size_t)(b * 173 + c) * 196 + n];
    __syncthreads();
    if (tid < 196) {
        float acc = 0.f;
        const float* Ar = &A[(size_t)(b * 196 + tid) * 196];
        for (int j = 0; j < 196; ++j) acc += Ar[j] * qs[j];
        fea[(size_t)(b * 173 + c) * 196 + tid] = acc;
    }
}

// ---------------- final classifier ----------------
__global__ void k_finale(const float* __restrict__ toh, const float* __restrict__ tnm,
                         const float* __restrict__ cms, const float* __restrict__ cls_w,
                         const float* __restrict__ cls_b, float* __restrict__ out) {
    int b = blockIdx.x;
    __shared__ float pcm[173];
    __shared__ float r1[4], r2[4];
    int tid = threadIdx.x;
    float a = (tid < 196) ? toh[b * 196 + tid] : 0.f;
    float c = (tid < 196) ? tnm[b * 196 + tid] : 0.f;
    for (int sh = 32; sh; sh >>= 1) { a += __shfl_xor(a, sh); c += __shfl_xor(c, sh); }
    if ((tid & 63) == 0) { r1[tid >> 6] = a; r2[tid >> 6] = c; }
    if (tid < 173) {
        float s = 0.f;
        const float* p = &cms[(size_t)(b * 173 + tid) * 196];
        for (int n = 0; n < 196; ++n) s += p[n];
        pcm[tid] = s;
    }
    __syncthreads();
    if (tid < 2) {
        float soh = r1[0] + r1[1] + r1[2] + r1[3];
        float snm = r2[0] + r2[1] + r2[2] + r2[3];
        const float* wrow = &cls_w[tid * 218];
        float acc = cls_b[tid];
        float w1 = 0.f, w2 = 0.f;
        for (int k = 0; k < 30; ++k) w1 += wrow[k];
        for (int k = 30; k < 45; ++k) w2 += wrow[k];
        acc += soh * w1 + snm * w2;
        for (int k = 0; k < 173; ++k) acc += wrow[45 + k] * pcm[k];
        out[b * 2 + tid] = acc;
    }
}

// ---------------------------------------------------------------------------
extern "C" void kernel_launch(void* const* d_in, const int* in_sizes, int n_in,
                              void* d_out, int out_size, void* d_ws, size_t ws_size,
                              hipStream_t stream) {
    const float* x      = (const float*)d_in[0];
    const float* oneHot = (const float*)d_in[1];
    const float* num    = (const float*)d_in[2];
    const float* c1_w1  = (const float*)d_in[3];
    const float* c1_g1  = (const float*)d_in[5];
    const float* c1_be1 = (const float*)d_in[6];
    const float* c1_w2  = (const float*)d_in[7];
    const float* c1_g2  = (const float*)d_in[9];
    const float* c1_be2 = (const float*)d_in[10];
    const float* oh_w   = (const float*)d_in[11];
    const float* oh_b   = (const float*)d_in[12];
    const float* oh_g   = (const float*)d_in[13];
    const float* oh_be  = (const float*)d_in[14];
    const float* nm_w   = (const float*)d_in[15];
    const float* nm_b   = (const float*)d_in[16];
    const float* nm_g   = (const float*)d_in[17];
    const float* nm_be  = (const float*)d_in[18];
    const float* gm1_w  = (const float*)d_in[19];
    const float* gm1_b  = (const float*)d_in[20];
    const float* gm2_w  = (const float*)d_in[21];
    const float* gm2_b  = (const float*)d_in[22];
    const float* ln1_g  = (const float*)d_in[23];
    const float* ln1_b  = (const float*)d_in[24];
    const float* ln2_g  = (const float*)d_in[25];
    const float* ln2_b  = (const float*)d_in[26];
    const float* e1_w   = (const float*)d_in[27];
    const float* e1_b   = (const float*)d_in[28];
    const float* e2_w   = (const float*)d_in[29];
    const float* e2_b   = (const float*)d_in[30];
    const float* f1_w   = (const float*)d_in[31];
    const float* f1_b   = (const float*)d_in[32];
    const float* f2_w   = (const float*)d_in[33];
    const float* f2_b   = (const float*)d_in[34];
    const float* f3_w   = (const float*)d_in[35];
    const float* f3_b   = (const float*)d_in[36];
    const float* f4_w   = (const float*)d_in[37];
    const float* f4_b   = (const float*)d_in[38];
    const float* cm_w   = (const float*)d_in[39];
    const float* cm_b   = (const float*)d_in[40];
    const float* cmf_w  = (const float*)d_in[41];
    const float* cmf_b  = (const float*)d_in[42];
    const float* cls_w  = (const float*)d_in[43];
    const float* cls_b  = (const float*)d_in[44];
    float* out = (float*)d_out;
    float* W = (float*)d_ws;

    // ---- workspace layout (floats) ----
    const size_t L = 802816;   // 32*128*196
    const size_t T = 282240;   // 32*45*196
    const size_t F3 = 1085056; // 32*173*196
    const size_t S2 = 1229312; // 32*196*196
    const size_t o_A = 0;             // conv1 raw -> h -> gcn tmp1 -> iq -> ci
    const size_t o_B = L;             // conv2 raw -> conv5(f) -> c5f_ln
    const size_t o_C = 2 * L;         // conv5 post-gcn (c5f)
    const size_t o_L1 = 3 * L;        // img_fea
    const size_t o_L2 = 4 * L;        // it_fea
    const size_t o_t1 = 5 * L;        // text(f) -> tq -> ct
    const size_t o_t2 = o_t1 + T;     // gcn2 tmp -> txf_ln
    const size_t o_t3 = o_t2 + T;     // text post-gcn (txf)
    const size_t o_t5 = o_t3 + T;     // text_fea
    const size_t o_t6 = o_t5 + T;     // ti_fea
    const size_t o_d1 = o_t6 + T;     // dist1 / att_ii  (32*128*128)
    const size_t o_ait = o_d1 + 524288;   // att_it (32*128*45)
    const size_t o_ati = o_ait + 184320;  // att_ti (32*45*128)
    const size_t o_d2 = o_ati + 184320;   // dist2 / att_tt (32*45*45)
    const size_t o_toh = o_d2 + 64800;
    const size_t o_tnm = o_toh + 6272;
    const size_t o_st = o_tnm + 6272;     // bn stats (2*128 *2)
    const size_t o_wT = o_st + 1024;      // 8 transposed 196x196
    const size_t o_feat = o_wT + 8 * 38416;
    const size_t o_q = o_feat + F3;       // q_cmsa, later cmsa_out
    const size_t o_Acm = o_q + F3;        // [32,196,196]
    const size_t o_fea = o_Acm + S2;      // cmsa fea
    // total ~44.8 MB

    float* gm1T = W + o_wT + 0 * 38416;
    float* gm2T = W + o_wT + 1 * 38416;
    float* e1T  = W + o_wT + 2 * 38416;
    float* e2T  = W + o_wT + 3 * 38416;
    float* f1T  = W + o_wT + 4 * 38416;
    float* f2T  = W + o_wT + 5 * 38416;
    float* f3T  = W + o_wT + 6 * 38416;
    float* f4T  = W + o_wT + 7 * 38416;

    // ---- weight transposes ----
    k_transpose<<<196, 256, 0, stream>>>(gm1_w, gm1T, 196, 196);
    k_transpose<<<196, 256, 0, stream>>>(gm2_w, gm2T, 196, 196);
    k_transpose<<<196, 256, 0, stream>>>(e1_w, e1T, 196, 196);
    k_transpose<<<196, 256, 0, stream>>>(e2_w, e2T, 196, 196);
    k_transpose<<<196, 256, 0, stream>>>(f1_w, f1T, 196, 196);
    k_transpose<<<196, 256, 0, stream>>>(f2_w, f2T, 196, 196);
    k_transpose<<<196, 256, 0, stream>>>(f3_w, f3T, 196, 196);
    k_transpose<<<196, 256, 0, stream>>>(f4_w, f4T, 196, 196);

    // ---- conv1 + BN + relu ----
    k_conv3d<<<dim3(16, 32), 256, 0, stream>>>(x, c1_w1, W + o_A, 320, 128);
    k_bn_stats<<<128, 256, 0, stream>>>(W + o_A, W + o_st, 128);
    k_bn_apply_relu<<<4096, 256, 0, stream>>>(W + o_A, W + o_st, c1_g1, c1_be1, 128);

    // ---- conv2 + BN + relu -> conv5(f) in B ----
    k_conv3d<<<dim3(16, 32), 256, 0, stream>>>(W + o_A, c1_w2, W + o_B, 128, 128);
    k_bn_stats<<<128, 256, 0, stream>>>(W + o_B, W + o_st + 512, 128);
    k_bn_apply_relu<<<4096, 256, 0, stream>>>(W + o_B, W + o_st + 512, c1_g2, c1_be2, 128);

    // ---- catnum (oneHot / num) ----
    k_catnum<<<196, 64, 0, stream>>>(oneHot, 24, oh_w, oh_b, oh_g, oh_be, W + o_toh);
    k_catnum<<<196, 64, 0, stream>>>(num, 11, nm_w, nm_b, nm_g, nm_be, W + o_tnm);
    k_textbuild<<<32 * 45, 256, 0, stream>>>(W + o_toh, W + o_tnm, W + o_t1);

    // ---- GCN on conv5 (C=128): f=B, tmp=A, out=C ----
    k_gcn_dist<<<4096, 128, 0, stream>>>(W + o_B, W + o_d1, 128);
    k_gcn_spmm<<<4096, 256, 0, stream>>>(W + o_d1, W + o_B, W + o_A, 128);
    k_gcn_fin<<<4096, 256, 0, stream>>>(W + o_A, gm1T, gm1_b, W + o_B, W + o_C);

    // ---- GCN on text (C=45): f=t1, tmp=t2, out=t3 ----
    k_gcn_dist<<<1440, 64, 0, stream>>>(W + o_t1, W + o_d2, 45);
    k_gcn_spmm<<<1440, 256, 0, stream>>>(W + o_d2, W + o_t1, W + o_t2, 45);
    k_gcn_fin<<<1440, 256, 0, stream>>>(W + o_t2, gm2T, gm2_b, W + o_t1, W + o_t3);

    // ---- LayerNorms: c5f_ln -> B, txf_ln -> t2 ----
    k_ln<<<4096, 64, 0, stream>>>(W + o_C, ln1_g, ln1_b, W + o_B);
    k_ln<<<1440, 64, 0, stream>>>(W + o_t3, ln2_g, ln2_b, W + o_t2);

    // ---- iq -> A, tq -> t1 ----
    k_lin<1><<<4096, 256, 0, stream>>>(W + o_B, e1T, e1_b, W + o_A);
    k_lin<1><<<1440, 256, 0, stream>>>(W + o_t2, e2T, e2_b, W + o_t1);

    // ---- attention matrices ----
    k_att<<<dim3(128, 32), 128, 0, stream>>>(W + o_A, W + o_A, W + o_d1, 128);  // att_ii
    k_att<<<dim3(45, 32), 64, 0, stream>>>(W + o_t1, W + o_t1, W + o_d2, 45);   // att_tt
    k_att<<<dim3(128, 32), 64, 0, stream>>>(W + o_A, W + o_t1, W + o_ait, 45);  // att_it
    k_att<<<dim3(45, 32), 128, 0, stream>>>(W + o_t1, W + o_A, W + o_ati, 128); // att_ti

    // ---- attention-weighted values ----
    k_attv<<<dim3(128, 32), 256, 0, stream>>>(W + o_d1, W + o_A, W + o_L1, 128);  // img_fea
    k_attv<<<dim3(45, 32), 256, 0, stream>>>(W + o_d2, W + o_t1, W + o_t5, 45);   // text_fea
    k_attv<<<dim3(128, 32), 256, 0, stream>>>(W + o_ait, W + o_t1, W + o_L2, 45); // it_fea
    k_attv<<<dim3(45, 32), 256, 0, stream>>>(W + o_ati, W + o_A, W + o_t6, 128);  // ti_fea

    // ---- ci -> A, ct -> t1 ----
    k_fuse2<<<4096, 256, 0, stream>>>(W + o_L1, f1T, f1_b, W + o_L2, f3T, f3_b,
                                      W + o_B, W + o_A);
    k_fuse2<<<1440, 256, 0, stream>>>(W + o_t5, f2T, f2_b, W + o_t6, f4T, f4_b,
                                      W + o_t2, W + o_t1);

    // ---- feat ----
    k_featbuild<<<32 * 173, 256, 0, stream>>>(W + o_A, W + o_C, W + o_t1, W + o_t3,
                                              W + o_feat);

    // ---- CMSA ----
    k_conv1x1<0><<<dim3(173, 32), 256, 0, stream>>>(W + o_feat, cm_w, cm_b, nullptr,
                                                    W + o_q, 173);
    k_cmsa_att<<<dim3(196, 32), 256, 0, stream>>>(W + o_q, W + o_Acm);
    k_cmsa_apply<<<dim3(173, 32), 256, 0, stream>>>(W + o_Acm, W + o_q, W + o_fea);
    k_conv1x1<1><<<dim3(173, 32), 256, 0, stream>>>(W + o_fea, cmf_w, cmf_b, W + o_feat,
                                                    W + o_q, 173);

    // ---- final classifier ----
    k_finale<<<32, 256, 0, stream>>>(W + o_toh, W + o_tnm, W + o_q, cls_w, cls_b, out);
}

// Round 2
// 1601.502 us; speedup vs baseline: 1.1452x; 1.1452x over previous
//
#include <hip/hip_runtime.h>
#include <hip/hip_bf16.h>

// ---------------------------------------------------------------------------
// Full fp32 implementation of the mv3Dunet_down_text_cmsa forward pass.
// B=32, spatial 4x7x7 (196), conv ch 320->128->128, text 45 ch, feat 173 ch.
// Round 2: register-blocked conv3d (4x7 outputs/thread), IC-split across
// blocks with partial-sum reduce, conflict-free LDS layout.
// ---------------------------------------------------------------------------

// ---------------- fused transpose of 8 [196,196] matrices ----------------
struct P8 { const float* p[8]; };
__global__ void k_transpose8(P8 ws_in, float* __restrict__ wt) {
    int i = blockIdx.x, m = blockIdx.y;
    const float* w = ws_in.p[m];
    float* o = wt + (size_t)m * 38416;
    for (int t = threadIdx.x; t < 196; t += blockDim.x)
        o[(size_t)i * 196 + t] = w[(size_t)t * 196 + i];
}

// ---------------- 3x3x3 'same' conv, NCDHW, bias omitted (BN cancels it) ----
// Thread = (oc_local 0..31, h 0..6); outputs acc[4][7] (all d, all w).
// Grid = (OC/32, G, B); input channels split into G groups; partial sums out.
#define OCT 32
#define CCH 4
__global__ __launch_bounds__(256, 4) void k_conv3d_v2(
    const float* __restrict__ x, const float* __restrict__ w,
    float* __restrict__ part, int IC, int icg, int OC) {
    __shared__ float xs[CCH][6][9][12];    // zero-padded input tile
    __shared__ float wsh[OCT][CCH][28];    // stride 28 keeps 16B alignment
    const int tid = threadIdx.x;
    const int ot = blockIdx.x, g = blockIdx.y, b = blockIdx.z;
    const int o0 = ot * OCT;
    const int cbase = g * icg;

    for (int i = tid; i < CCH * 648; i += 256) ((float*)xs)[i] = 0.f;

    const int ol = tid / 7;
    const int h = tid - ol * 7;
    const bool active = tid < 224;

    float acc[4][7];
#pragma unroll
    for (int d = 0; d < 4; ++d)
#pragma unroll
        for (int i = 0; i < 7; ++i) acc[d][i] = 0.f;

    for (int c0 = 0; c0 < icg; c0 += CCH) {
        __syncthreads();
        for (int i = tid; i < CCH * 196; i += 256) {
            int cc = i / 196, ss = i - cc * 196;
            int dd = ss / 49, rr = ss - dd * 49;
            int hh = rr / 7, ww = rr - hh * 7;
            xs[cc][dd + 1][hh + 1][ww + 1] =
                x[(size_t)(b * IC + cbase + c0 + cc) * 196 + ss];
        }
        for (int i = tid; i < OCT * CCH * 27; i += 256) {
            int oo = i / (CCH * 27);
            int r = i - oo * CCH * 27;
            int cc = r / 27, k = r - cc * 27;
            wsh[oo][cc][k] = w[(size_t)((o0 + oo) * IC + cbase + c0 + cc) * 27 + k];
        }
        __syncthreads();
        if (!active) continue;
        for (int cc = 0; cc < CCH; ++cc) {
            float wr[27];
            const float* wp = &wsh[ol][cc][0];
#pragma unroll
            for (int k = 0; k < 27; ++k) wr[k] = wp[k];
#pragma unroll
            for (int pd = 0; pd < 6; ++pd) {
#pragma unroll
                for (int ph = 0; ph < 3; ++ph) {
                    const float* row = &xs[cc][pd][h + ph][0];
                    float r[9];
#pragma unroll
                    for (int k = 0; k < 9; ++k) r[k] = row[k];
#pragma unroll
                    for (int kd = 0; kd < 3; ++kd) {
                        int d = pd - kd;
                        if (d >= 0 && d < 4) {
                            float w0 = wr[kd * 9 + ph * 3 + 0];
                            float w1 = wr[kd * 9 + ph * 3 + 1];
                            float w2 = wr[kd * 9 + ph * 3 + 2];
#pragma unroll
                            for (int i = 0; i < 7; ++i) {
                                acc[d][i] += r[i] * w0;
                                acc[d][i] += r[i + 1] * w1;
                                acc[d][i] += r[i + 2] * w2;
                            }
                        }
                    }
                }
            }
        }
    }
    if (active) {
        float* yp = &part[((size_t)g * 32 + b) * OC * 196 +
                          (size_t)(o0 + ol) * 196 + h * 7];
#pragma unroll
        for (int d = 0; d < 4; ++d)
#pragma unroll
            for (int i = 0; i < 7; ++i) yp[d * 49 + i] = acc[d][i];
    }
}

// sum G=8 partials
__global__ void k_reduce_part(const float* __restrict__ part, float* __restrict__ y,
                              int n) {
    int i = blockIdx.x * blockDim.x + threadIdx.x;
    if (i < n) {
        float s = 0.f;
#pragma unroll
        for (int g = 0; g < 8; ++g) s += part[(size_t)g * n + i];
        y[i] = s;
    }
}

// ---------------- BN (training mode, axes 0,2,3,4) ----------------
__global__ void k_bn_stats(const float* __restrict__ y, float* __restrict__ stats,
                           int C) {
    int ch = blockIdx.x; int tid = threadIdx.x;
    float s = 0.f, s2 = 0.f;
    for (int b = 0; b < 32; ++b) {
        const float* p = &y[(size_t)(b * C + ch) * 196];
        for (int i = tid; i < 196; i += 256) { float v = p[i]; s += v; s2 += v * v; }
    }
    __shared__ float r1[4], r2[4];
    for (int sh = 32; sh; sh >>= 1) { s += __shfl_xor(s, sh); s2 += __shfl_xor(s2, sh); }
    if ((tid & 63) == 0) { r1[tid >> 6] = s; r2[tid >> 6] = s2; }
    __syncthreads();
    if (tid == 0) {
        float S = r1[0] + r1[1] + r1[2] + r1[3];
        float S2 = r2[0] + r2[1] + r2[2] + r2[3];
        float m = S / 6272.f;
        float v = S2 / 6272.f - m * m;
        stats[2 * ch] = m;
        stats[2 * ch + 1] = rsqrtf(v + 1e-5f);
    }
}

__global__ void k_bn_apply_relu(float* __restrict__ y, const float* __restrict__ stats,
                                const float* __restrict__ g, const float* __restrict__ be,
                                int C) {
    int idx = blockIdx.x;           // b*C + ch
    int ch = idx % C;
    int s = threadIdx.x;
    if (s < 196) {
        float m = stats[2 * ch], r = stats[2 * ch + 1];
        float v = y[(size_t)idx * 196 + s];
        y[(size_t)idx * 196 + s] = fmaxf((v - m) * r * g[ch] + be[ch], 0.f);
    }
}

// ---------------- catnum: Linear(A->196) + BN over batch + SiLU -------------
__global__ void k_catnum(const float* __restrict__ inp, int A,
                         const float* __restrict__ w, const float* __restrict__ bias,
                         const float* __restrict__ g, const float* __restrict__ be,
                         float* __restrict__ outv) {
    int j = blockIdx.x;             // feature 0..195
    int lane = threadIdx.x;         // 64 threads, 32 active
    float v = 0.f;
    if (lane < 32) {
        v = bias[j];
        for (int k = 0; k < A; ++k) v += inp[lane * A + k] * w[j * A + k];
    }
    float s = (lane < 32) ? v : 0.f;
    float s2 = (lane < 32) ? v * v : 0.f;
    for (int m = 16; m; m >>= 1) { s += __shfl_xor(s, m, 32); s2 += __shfl_xor(s2, m, 32); }
    if (lane < 32) {
        float mean = s / 32.f;
        float var = s2 / 32.f - mean * mean;
        float rstd = rsqrtf(var + 1e-5f);
        float t = (v - mean) * rstd * g[j] + be[j];
        t = t / (1.f + expf(-t));   // SiLU
        outv[lane * 196 + j] = t;
    }
}

__global__ void k_textbuild(const float* __restrict__ toh, const float* __restrict__ tnm,
                            float* __restrict__ text) {
    int idx = blockIdx.x;           // b*45+c
    int b = idx / 45, c = idx - b * 45;
    int s = threadIdx.x;
    if (s < 196) text[(size_t)idx * 196 + s] = (c < 30) ? toh[b * 196 + s] : tnm[b * 196 + s];
}

// ---------------- GCN ----------------
__global__ void k_gcn_dist(const float* __restrict__ f, float* __restrict__ dist, int C) {
    int idx = blockIdx.x;           // b*C+i
    int b = idx / C;
    __shared__ float fi[196];
    int tid = threadIdx.x;
    for (int n = tid; n < 196; n += blockDim.x) fi[n] = f[(size_t)idx * 196 + n];
    __syncthreads();
    if (tid < C) {
        const float* fj = &f[(size_t)(b * C + tid) * 196];
        float s = 0.f;
        for (int n = 0; n < 196; ++n) s += fabsf(fi[n] - fj[n]);
        dist[(size_t)idx * C + tid] = expf(-s);
    }
}

__global__ void k_gcn_spmm(const float* __restrict__ dist, const float* __restrict__ f,
                           float* __restrict__ tmp, int C) {
    int idx = blockIdx.x;           // b*C+i
    int b = idx / C;
    __shared__ float ds[128];
    for (int j = threadIdx.x; j < C; j += 256) ds[j] = dist[(size_t)idx * C + j];
    __syncthreads();
    int n = threadIdx.x;
    if (n < 196) {
        float acc = 0.f;
        for (int j = 0; j < C; ++j) acc += ds[j] * f[(size_t)(b * C + j) * 196 + n];
        tmp[(size_t)idx * 196 + n] = acc;
    }
}

__global__ void k_gcn_fin(const float* __restrict__ tmp, const float* __restrict__ wt,
                          const float* __restrict__ bias, const float* __restrict__ f,
                          float* __restrict__ out) {
    int row = blockIdx.x;
    __shared__ float ts[196];
    for (int n = threadIdx.x; n < 196; n += 256) ts[n] = tmp[(size_t)row * 196 + n];
    __syncthreads();
    int k = threadIdx.x;
    if (k < 196) {
        float acc = bias[k];
        for (int n = 0; n < 196; ++n) acc += ts[n] * wt[n * 196 + k];
        out[(size_t)row * 196 + k] = fmaxf(acc, 0.f) + f[(size_t)row * 196 + k];
    }
}

// ---------------- LayerNorm over last dim (196), eps 1e-6 ----------------
__global__ void k_ln(const float* __restrict__ x, const float* __restrict__ g,
                     const float* __restrict__ be, float* __restrict__ out) {
    int row = blockIdx.x;
    int lane = threadIdx.x;         // 64
    float v[4]; float s = 0.f, s2 = 0.f;
#pragma unroll
    for (int k = 0; k < 4; ++k) {
        int n = lane + 64 * k;
        v[k] = (n < 196) ? x[(size_t)row * 196 + n] : 0.f;
        s += v[k]; s2 += v[k] * v[k];
    }
    for (int m = 32; m; m >>= 1) { s += __shfl_xor(s, m); s2 += __shfl_xor(s2, m); }
    float mean = s / 196.f;
    float var = s2 / 196.f - mean * mean;
    float rstd = rsqrtf(var + 1e-6f);
#pragma unroll
    for (int k = 0; k < 4; ++k) {
        int n = lane + 64 * k;
        if (n < 196) out[(size_t)row * 196 + n] = (v[k] - mean) * rstd * g[n] + be[n];
    }
}

// ---------------- row GEMV: out = act(x @ wt + b) ----------------
template <int RELU>
__global__ void k_lin(const float* __restrict__ x, const float* __restrict__ wt,
                      const float* __restrict__ bias, float* __restrict__ out) {
    int row = blockIdx.x;
    __shared__ float xs[196];
    for (int n = threadIdx.x; n < 196; n += 256) xs[n] = x[(size_t)row * 196 + n];
    __syncthreads();
    int o = threadIdx.x;
    if (o < 196) {
        float acc = bias[o];
        for (int n = 0; n < 196; ++n) acc += xs[n] * wt[n * 196 + o];
        out[(size_t)row * 196 + o] = RELU ? fmaxf(acc, 0.f) : acc;
    }
}

// out = x1@w1t + b1 + x2@w2t + b2 + res
__global__ void k_fuse2(const float* __restrict__ x1, const float* __restrict__ w1t,
                        const float* __restrict__ b1, const float* __restrict__ x2,
                        const float* __restrict__ w2t, const float* __restrict__ b2,
                        const float* __restrict__ res, float* __restrict__ out) {
    int row = blockIdx.x;
    __shared__ float s1[196], s2[196];
    for (int n = threadIdx.x; n < 196; n += 256) {
        s1[n] = x1[(size_t)row * 196 + n];
        s2[n] = x2[(size_t)row * 196 + n];
    }
    __syncthreads();
    int o = threadIdx.x;
    if (o < 196) {
        float acc = b1[o] + b2[o] + res[(size_t)row * 196 + o];
        for (int n = 0; n < 196; ++n)
            acc += s1[n] * w1t[n * 196 + o] + s2[n] * w2t[n * 196 + o];
        out[(size_t)row * 196 + o] = acc;
    }
}

// ---------------- attention: A = softmax(q @ k^T) ----------------
__global__ void k_att(const float* __restrict__ q, const float* __restrict__ k,
                      float* __restrict__ A, int R2) {
    int i = blockIdx.x, b = blockIdx.y, R1 = gridDim.x;
    __shared__ float qs[196];
    __shared__ float red[2];
    int tid = threadIdx.x;
    for (int n = tid; n < 196; n += blockDim.x) qs[n] = q[(size_t)(b * R1 + i) * 196 + n];
    __syncthreads();
    float sc = -1e30f;
    if (tid < R2) {
        const float* kr = &k[(size_t)(b * R2 + tid) * 196];
        float acc = 0.f;
        for (int n = 0; n < 196; ++n) acc += qs[n] * kr[n];
        sc = acc;
    }
    float m = sc;
    for (int sh = 32; sh; sh >>= 1) m = fmaxf(m, __shfl_xor(m, sh));
    int nw = blockDim.x >> 6;
    if (nw > 1) {
        if ((tid & 63) == 0) red[tid >> 6] = m;
        __syncthreads();
        m = fmaxf(red[0], red[1]);
        __syncthreads();
    }
    float e = (tid < R2) ? expf(sc - m) : 0.f;
    float s = e;
    for (int sh = 32; sh; sh >>= 1) s += __shfl_xor(s, sh);
    if (nw > 1) {
        if ((tid & 63) == 0) red[tid >> 6] = s;
        __syncthreads();
        s = red[0] + red[1];
    }
    if (tid < R2) A[(size_t)(b * R1 + i) * R2 + tid] = e / s;
}

// out[b,i,:] = sum_j A[b,i,j] * v[b,j,:]
__global__ void k_attv(const float* __restrict__ A, const float* __restrict__ v,
                       float* __restrict__ out, int R2) {
    int i = blockIdx.x, b = blockIdx.y, R1 = gridDim.x;
    __shared__ float as[128];
    int tid = threadIdx.x;
    for (int j = tid; j < R2; j += 256) as[j] = A[(size_t)(b * R1 + i) * R2 + j];
    __syncthreads();
    if (tid < 196) {
        float acc = 0.f;
        for (int j = 0; j < R2; ++j) acc += as[j] * v[(size_t)(b * R2 + j) * 196 + tid];
        out[(size_t)(b * R1 + i) * 196 + tid] = acc;
    }
}

// ---------------- feat = concat(ci + c5f, ct + txf) ----------------
__global__ void k_featbuild(const float* __restrict__ ci, const float* __restrict__ c5f,
                            const float* __restrict__ ct, const float* __restrict__ txf,
                            float* __restrict__ feat) {
    int idx = blockIdx.x;           // b*173+c
    int b = idx / 173, c = idx - b * 173;
    int s = threadIdx.x;
    if (s < 196) {
        float v;
        if (c < 128)
            v = ci[(size_t)(b * 128 + c) * 196 + s] + c5f[(size_t)(b * 128 + c) * 196 + s];
        else
            v = ct[(size_t)(b * 45 + c - 128) * 196 + s] + txf[(size_t)(b * 45 + c - 128) * 196 + s];
        feat[(size_t)idx * 196 + s] = v;
    }
}

// ---------------- 1x1x1 conv (channel mix), relu, optional residual --------
template <int RES>
__global__ void k_conv1x1(const float* __restrict__ x, const float* __restrict__ w,
                          const float* __restrict__ bias, const float* __restrict__ res,
                          float* __restrict__ out, int C) {
    int o = blockIdx.x, b = blockIdx.y;
    __shared__ float wsm[173];
    for (int c = threadIdx.x; c < C; c += 256) wsm[c] = w[o * C + c];
    __syncthreads();
    int s = threadIdx.x;
    if (s < 196) {
        float acc = bias[o];
        for (int c = 0; c < C; ++c) acc += wsm[c] * x[(size_t)(b * C + c) * 196 + s];
        acc = fmaxf(acc, 0.f);
        if (RES) acc += res[(size_t)(b * C + o) * 196 + s];
        out[(size_t)(b * C + o) * 196 + s] = acc;
    }
}

// ---------------- CMSA attention over positions ----------------
__global__ void k_cmsa_att(const float* __restrict__ q, float* __restrict__ A) {
    int i = blockIdx.x, b = blockIdx.y;   // i in [0,196)
    __shared__ float col[173];
    __shared__ float red[4];
    int tid = threadIdx.x;
    for (int c = tid; c < 173; c += 256) col[c] = q[(size_t)(b * 173 + c) * 196 + i];
    __syncthreads();
    float sc = -1e30f;
    if (tid < 196) {
        float acc = 0.f;
        for (int c = 0; c < 173; ++c) acc += col[c] * q[(size_t)(b * 173 + c) * 196 + tid];
        sc = acc;
    }
    float m = sc;
    for (int sh = 32; sh; sh >>= 1) m = fmaxf(m, __shfl_xor(m, sh));
    if ((tid & 63) == 0) red[tid >> 6] = m;
    __syncthreads();
    m = fmaxf(fmaxf(red[0], red[1]), fmaxf(red[2], red[3]));
    __syncthreads();
    float e = (tid < 196) ? expf(sc - m) : 0.f;
    float s = e;
    for (int sh = 32; sh; sh >>= 1) s += __shfl_xor(s, sh);
    if ((tid & 63) == 0) red[tid >> 6] = s;
    __syncthreads();
    s = red[0] + red[1] + red[2] + red[3];
    if (tid < 196) A[(size_t)(b * 196 + i) * 196 + tid] = e / s;
}

__global__ void k_cmsa_apply(const float* __restrict__ A, const float* __restrict__ q,
                             float* __restrict__ fea) {
    int c = blockIdx.x, b = blockIdx.y;
    __shared__ float qs[196];
    int tid = threadIdx.x;
    for (int n = tid; n < 196; n += 256) qs[n] = q[(size_t)(b * 173 + c) * 196 + n];
    __syncthreads();
    if (tid < 196) {
        float acc = 0.f;
        const float* Ar = &A[(size_t)(b * 196 + tid) * 196];
        for (int j = 0; j < 196; ++j) acc += Ar[j] * qs[j];
        fea[(size_t)(b * 173 + c) * 196 + tid] = acc;
    }
}

// ---------------- final classifier ----------------
__global__ void k_finale(const float* __restrict__ toh, const float* __restrict__ tnm,
                         const float* __restrict__ cms, const float* __restrict__ cls_w,
                         const float* __restrict__ cls_b, float* __restrict__ out) {
    int b = blockIdx.x;
    __shared__ float pcm[173];
    __shared__ float r1[4], r2[4];
    int tid = threadIdx.x;
    float a = (tid < 196) ? toh[b * 196 + tid] : 0.f;
    float c = (tid < 196) ? tnm[b * 196 + tid] : 0.f;
    for (int sh = 32; sh; sh >>= 1) { a += __shfl_xor(a, sh); c += __shfl_xor(c, sh); }
    if ((tid & 63) == 0) { r1[tid >> 6] = a; r2[tid >> 6] = c; }
    if (tid < 173) {
        float s = 0.f;
        const float* p = &cms[(size_t)(b * 173 + tid) * 196];
        for (int n = 0; n < 196; ++n) s += p[n];
        pcm[tid] = s;
    }
    __syncthreads();
    if (tid < 2) {
        float soh = r1[0] + r1[1] + r1[2] + r1[3];
        float snm = r2[0] + r2[1] + r2[2] + r2[3];
        const float* wrow = &cls_w[tid * 218];
        float acc = cls_b[tid];
        float w1 = 0.f, w2 = 0.f;
        for (int k = 0; k < 30; ++k) w1 += wrow[k];
        for (int k = 30; k < 45; ++k) w2 += wrow[k];
        acc += soh * w1 + snm * w2;
        for (int k = 0; k < 173; ++k) acc += wrow[45 + k] * pcm[k];
        out[b * 2 + tid] = acc;
    }
}

// ---------------------------------------------------------------------------
extern "C" void kernel_launch(void* const* d_in, const int* in_sizes, int n_in,
                              void* d_out, int out_size, void* d_ws, size_t ws_size,
                              hipStream_t stream) {
    const float* x      = (const float*)d_in[0];
    const float* oneHot = (const float*)d_in[1];
    const float* num    = (const float*)d_in[2];
    const float* c1_w1  = (const float*)d_in[3];
    const float* c1_g1  = (const float*)d_in[5];
    const float* c1_be1 = (const float*)d_in[6];
    const float* c1_w2  = (const float*)d_in[7];
    const float* c1_g2  = (const float*)d_in[9];
    const float* c1_be2 = (const float*)d_in[10];
    const float* oh_w   = (const float*)d_in[11];
    const float* oh_b   = (const float*)d_in[12];
    const float* oh_g   = (const float*)d_in[13];
    const float* oh_be  = (const float*)d_in[14];
    const float* nm_w   = (const float*)d_in[15];
    const float* nm_b   = (const float*)d_in[16];
    const float* nm_g   = (const float*)d_in[17];
    const float* nm_be  = (const float*)d_in[18];
    const float* gm1_w  = (const float*)d_in[19];
    const float* gm1_b  = (const float*)d_in[20];
    const float* gm2_w  = (const float*)d_in[21];
    const float* gm2_b  = (const float*)d_in[22];
    const float* ln1_g  = (const float*)d_in[23];
    const float* ln1_b  = (const float*)d_in[24];
    const float* ln2_g  = (const float*)d_in[25];
    const float* ln2_b  = (const float*)d_in[26];
    const float* e1_w   = (const float*)d_in[27];
    const float* e1_b   = (const float*)d_in[28];
    const float* e2_w   = (const float*)d_in[29];
    const float* e2_b   = (const float*)d_in[30];
    const float* f1_w   = (const float*)d_in[31];
    const float* f1_b   = (const float*)d_in[32];
    const float* f2_w   = (const float*)d_in[33];
    const float* f2_b   = (const float*)d_in[34];
    const float* f3_w   = (const float*)d_in[35];
    const float* f3_b   = (const float*)d_in[36];
    const float* f4_w   = (const float*)d_in[37];
    const float* f4_b   = (const float*)d_in[38];
    const float* cm_w   = (const float*)d_in[39];
    const float* cm_b   = (const float*)d_in[40];
    const float* cmf_w  = (const float*)d_in[41];
    const float* cmf_b  = (const float*)d_in[42];
    const float* cls_w  = (const float*)d_in[43];
    const float* cls_b  = (const float*)d_in[44];
    float* out = (float*)d_out;
    float* W = (float*)d_ws;

    // ---- workspace layout (floats) ----
    const size_t L = 802816;   // 32*128*196
    const size_t T = 282240;   // 32*45*196
    const size_t F3 = 1085056; // 32*173*196
    const size_t S2 = 1229312; // 32*196*196
    const size_t o_A = 0;             // conv1 -> h -> gcn tmp1 -> iq -> ci
    const size_t o_B = L;             // conv2 -> conv5(f) -> c5f_ln
    const size_t o_C = 2 * L;         // conv5 post-gcn (c5f)
    const size_t o_L1 = 3 * L;        // img_fea        (also conv partials)
    const size_t o_L2 = 4 * L;        // it_fea
    const size_t o_t1 = 5 * L;        // text(f) -> tq -> ct
    const size_t o_t2 = o_t1 + T;     // gcn2 tmp -> txf_ln
    const size_t o_t3 = o_t2 + T;     // text post-gcn (txf)
    const size_t o_t5 = o_t3 + T;     // text_fea
    const size_t o_t6 = o_t5 + T;     // ti_fea
    const size_t o_d1 = o_t6 + T;     // dist1 / att_ii  (32*128*128)
    const size_t o_ait = o_d1 + 524288;   // att_it (32*128*45)
    const size_t o_ati = o_ait + 184320;  // att_ti (32*45*128)
    const size_t o_d2 = o_ati + 184320;   // dist2 / att_tt (32*45*45)
    const size_t o_toh = o_d2 + 64800;
    const size_t o_tnm = o_toh + 6272;
    const size_t o_st = o_tnm + 6272;     // bn stats
    const size_t o_wT = o_st + 1024;      // 8 transposed 196x196
    const size_t o_feat = o_wT + 8 * 38416;
    const size_t o_q = o_feat + F3;       // q_cmsa, later cmsa_out
    const size_t o_Acm = o_q + F3;        // [32,196,196]
    const size_t o_fea = o_Acm + S2;      // cmsa fea
    // total ~44.8 MB; conv partials [3L, 11L) overlap post-conv-only buffers

    float* part = W + o_L1;               // 8*L floats of partials
    float* gm1T = W + o_wT + 0 * 38416;
    float* gm2T = W + o_wT + 1 * 38416;
    float* e1T  = W + o_wT + 2 * 38416;
    float* e2T  = W + o_wT + 3 * 38416;
    float* f1T  = W + o_wT + 4 * 38416;
    float* f2T  = W + o_wT + 5 * 38416;
    float* f3T  = W + o_wT + 6 * 38416;
    float* f4T  = W + o_wT + 7 * 38416;

    // ---- conv1 + reduce + BN + relu -> A ----
    k_conv3d_v2<<<dim3(4, 8, 32), 256, 0, stream>>>(x, c1_w1, part, 320, 40, 128);
    k_reduce_part<<<3136, 256, 0, stream>>>(part, W + o_A, 802816);
    k_bn_stats<<<128, 256, 0, stream>>>(W + o_A, W + o_st, 128);
    k_bn_apply_relu<<<4096, 256, 0, stream>>>(W + o_A, W + o_st, c1_g1, c1_be1, 128);

    // ---- conv2 + reduce + BN + relu -> conv5(f) in B ----
    k_conv3d_v2<<<dim3(4, 8, 32), 256, 0, stream>>>(W + o_A, c1_w2, part, 128, 16, 128);
    k_reduce_part<<<3136, 256, 0, stream>>>(part, W + o_B, 802816);
    k_bn_stats<<<128, 256, 0, stream>>>(W + o_B, W + o_st + 512, 128);
    k_bn_apply_relu<<<4096, 256, 0, stream>>>(W + o_B, W + o_st + 512, c1_g2, c1_be2, 128);

    // ---- weight transposes (AFTER convs: partials overlap o_wT) ----
    P8 p8;
    p8.p[0] = gm1_w; p8.p[1] = gm2_w; p8.p[2] = e1_w; p8.p[3] = e2_w;
    p8.p[4] = f1_w;  p8.p[5] = f2_w;  p8.p[6] = f3_w; p8.p[7] = f4_w;
    k_transpose8<<<dim3(196, 8), 256, 0, stream>>>(p8, W + o_wT);

    // ---- catnum (oneHot / num) ----
    k_catnum<<<196, 64, 0, stream>>>(oneHot, 24, oh_w, oh_b, oh_g, oh_be, W + o_toh);
    k_catnum<<<196, 64, 0, stream>>>(num, 11, nm_w, nm_b, nm_g, nm_be, W + o_tnm);
    k_textbuild<<<32 * 45, 256, 0, stream>>>(W + o_toh, W + o_tnm, W + o_t1);

    // ---- GCN on conv5 (C=128): f=B, tmp=A, out=C ----
    k_gcn_dist<<<4096, 128, 0, stream>>>(W + o_B, W + o_d1, 128);
    k_gcn_spmm<<<4096, 256, 0, stream>>>(W + o_d1, W + o_B, W + o_A, 128);
    k_gcn_fin<<<4096, 256, 0, stream>>>(W + o_A, gm1T, gm1_b, W + o_B, W + o_C);

    // ---- GCN on text (C=45): f=t1, tmp=t2, out=t3 ----
    k_gcn_dist<<<1440, 64, 0, stream>>>(W + o_t1, W + o_d2, 45);
    k_gcn_spmm<<<1440, 256, 0, stream>>>(W + o_d2, W + o_t1, W + o_t2, 45);
    k_gcn_fin<<<1440, 256, 0, stream>>>(W + o_t2, gm2T, gm2_b, W + o_t1, W + o_t3);

    // ---- LayerNorms: c5f_ln -> B, txf_ln -> t2 ----
    k_ln<<<4096, 64, 0, stream>>>(W + o_C, ln1_g, ln1_b, W + o_B);
    k_ln<<<1440, 64, 0, stream>>>(W + o_t3, ln2_g, ln2_b, W + o_t2);

    // ---- iq -> A, tq -> t1 ----
    k_lin<1><<<4096, 256, 0, stream>>>(W + o_B, e1T, e1_b, W + o_A);
    k_lin<1><<<1440, 256, 0, stream>>>(W + o_t2, e2T, e2_b, W + o_t1);

    // ---- attention matrices ----
    k_att<<<dim3(128, 32), 128, 0, stream>>>(W + o_A, W + o_A, W + o_d1, 128);  // att_ii
    k_att<<<dim3(45, 32), 64, 0, stream>>>(W + o_t1, W + o_t1, W + o_d2, 45);   // att_tt
    k_att<<<dim3(128, 32), 64, 0, stream>>>(W + o_A, W + o_t1, W + o_ait, 45);  // att_it
    k_att<<<dim3(45, 32), 128, 0, stream>>>(W + o_t1, W + o_A, W + o_ati, 128); // att_ti

    // ---- attention-weighted values ----
    k_attv<<<dim3(128, 32), 256, 0, stream>>>(W + o_d1, W + o_A, W + o_L1, 128);  // img_fea
    k_attv<<<dim3(45, 32), 256, 0, stream>>>(W + o_d2, W + o_t1, W + o_t5, 45);   // text_fea
    k_attv<<<dim3(128, 32), 256, 0, stream>>>(W + o_ait, W + o_t1, W + o_L2, 45); // it_fea
    k_attv<<<dim3(45, 32), 256, 0, stream>>>(W + o_ati, W + o_A, W + o_t6, 128);  // ti_fea

    // ---- ci -> A, ct -> t1 ----
    k_fuse2<<<4096, 256, 0, stream>>>(W + o_L1, f1T, f1_b, W + o_L2, f3T, f3_b,
                                      W + o_B, W + o_A);
    k_fuse2<<<1440, 256, 0, stream>>>(W + o_t5, f2T, f2_b, W + o_t6, f4T, f4_b,
                                      W + o_t2, W + o_t1);

    // ---- feat ----
    k_featbuild<<<32 * 173, 256, 0, stream>>>(W + o_A, W + o_C, W + o_t1, W + o_t3,
                                              W + o_feat);

    // ---- CMSA ----
    k_conv1x1<0><<<dim3(173, 32), 256, 0, stream>>>(W + o_feat, cm_w, cm_b, nullptr,
                                                    W + o_q, 173);
    k_cmsa_att<<<dim3(196, 32), 256, 0, stream>>>(W + o_q, W + o_Acm);
    k_cmsa_apply<<<dim3(173, 32), 256, 0, stream>>>(W + o_Acm, W + o_q, W + o_fea);
    k_conv1x1<1><<<dim3(173, 32), 256, 0, stream>>>(W + o_fea, cmf_w, cmf_b, W + o_feat,
                                                    W + o_q, 173);

    // ---- final classifier ----
    k_finale<<<32, 256, 0, stream>>>(W + o_toh, W + o_tnm, W + o_q, cls_w, cls_b, out);
}

// Round 3
// 1040.052 us; speedup vs baseline: 1.7634x; 1.5398x over previous
//
#include <hip/hip_runtime.h>
#include <hip/hip_bf16.h>

// ---------------------------------------------------------------------------
// Full fp32 implementation of the mv3Dunet_down_text_cmsa forward pass.
// B=32, spatial 4x7x7 (196), conv ch 320->128->128, text 45 ch, feat 173 ch.
// Round 3: same register-blocked conv3d, but launch_bounds relaxed to
// (256,2): round-2's (256,4) clamped VGPRs to 64 and spilled ~2.2 GB of
// scratch per conv dispatch (measured WRITE_SIZE), making it scratch-BW-bound.
// ---------------------------------------------------------------------------

// ---------------- fused transpose of 8 [196,196] matrices ----------------
struct P8 { const float* p[8]; };
__global__ void k_transpose8(P8 ws_in, float* __restrict__ wt) {
    int i = blockIdx.x, m = blockIdx.y;
    const float* w = ws_in.p[m];
    float* o = wt + (size_t)m * 38416;
    for (int t = threadIdx.x; t < 196; t += blockDim.x)
        o[(size_t)i * 196 + t] = w[(size_t)t * 196 + i];
}

// ---------------- 3x3x3 'same' conv, NCDHW, bias omitted (BN cancels it) ----
// Thread = (oc_local 0..31, h 0..6); outputs acc[4][7] (all d, all w).
// Grid = (OC/32, G, B); input channels split into G groups; partial sums out.
#define OCT 32
#define CCH 4
__global__ __launch_bounds__(256, 2) void k_conv3d_v2(
    const float* __restrict__ x, const float* __restrict__ w,
    float* __restrict__ part, int IC, int icg, int OC) {
    __shared__ float xs[CCH][6][9][12];    // zero-padded input tile
    __shared__ float wsh[OCT][CCH][28];    // stride 28 keeps 16B alignment
    const int tid = threadIdx.x;
    const int ot = blockIdx.x, g = blockIdx.y, b = blockIdx.z;
    const int o0 = ot * OCT;
    const int cbase = g * icg;

    for (int i = tid; i < CCH * 648; i += 256) ((float*)xs)[i] = 0.f;

    const int ol = tid / 7;
    const int h = tid - ol * 7;
    const bool active = tid < 224;

    float acc[4][7];
#pragma unroll
    for (int d = 0; d < 4; ++d)
#pragma unroll
        for (int i = 0; i < 7; ++i) acc[d][i] = 0.f;

    for (int c0 = 0; c0 < icg; c0 += CCH) {
        __syncthreads();
        for (int i = tid; i < CCH * 196; i += 256) {
            int cc = i / 196, ss = i - cc * 196;
            int dd = ss / 49, rr = ss - dd * 49;
            int hh = rr / 7, ww = rr - hh * 7;
            xs[cc][dd + 1][hh + 1][ww + 1] =
                x[(size_t)(b * IC + cbase + c0 + cc) * 196 + ss];
        }
        for (int i = tid; i < OCT * CCH * 27; i += 256) {
            int oo = i / (CCH * 27);
            int r = i - oo * CCH * 27;
            int cc = r / 27, k = r - cc * 27;
            wsh[oo][cc][k] = w[(size_t)((o0 + oo) * IC + cbase + c0 + cc) * 27 + k];
        }
        __syncthreads();
        if (!active) continue;
        for (int cc = 0; cc < CCH; ++cc) {
            float wr[27];
            const float* wp = &wsh[ol][cc][0];
#pragma unroll
            for (int k = 0; k < 27; ++k) wr[k] = wp[k];
#pragma unroll
            for (int pd = 0; pd < 6; ++pd) {
#pragma unroll
                for (int ph = 0; ph < 3; ++ph) {
                    const float* row = &xs[cc][pd][h + ph][0];
                    float r[9];
#pragma unroll
                    for (int k = 0; k < 9; ++k) r[k] = row[k];
#pragma unroll
                    for (int kd = 0; kd < 3; ++kd) {
                        int d = pd - kd;
                        if (d >= 0 && d < 4) {
                            float w0 = wr[kd * 9 + ph * 3 + 0];
                            float w1 = wr[kd * 9 + ph * 3 + 1];
                            float w2 = wr[kd * 9 + ph * 3 + 2];
#pragma unroll
                            for (int i = 0; i < 7; ++i) {
                                acc[d][i] += r[i] * w0;
                                acc[d][i] += r[i + 1] * w1;
                                acc[d][i] += r[i + 2] * w2;
                            }
                        }
                    }
                }
            }
        }
    }
    if (active) {
        float* yp = &part[((size_t)g * 32 + b) * OC * 196 +
                          (size_t)(o0 + ol) * 196 + h * 7];
#pragma unroll
        for (int d = 0; d < 4; ++d)
#pragma unroll
            for (int i = 0; i < 7; ++i) yp[d * 49 + i] = acc[d][i];
    }
}

// sum G=8 partials
__global__ void k_reduce_part(const float* __restrict__ part, float* __restrict__ y,
                              int n) {
    int i = blockIdx.x * blockDim.x + threadIdx.x;
    if (i < n) {
        float s = 0.f;
#pragma unroll
        for (int g = 0; g < 8; ++g) s += part[(size_t)g * n + i];
        y[i] = s;
    }
}

// ---------------- BN (training mode, axes 0,2,3,4) ----------------
__global__ void k_bn_stats(const float* __restrict__ y, float* __restrict__ stats,
                           int C) {
    int ch = blockIdx.x; int tid = threadIdx.x;
    float s = 0.f, s2 = 0.f;
    for (int b = 0; b < 32; ++b) {
        const float* p = &y[(size_t)(b * C + ch) * 196];
        for (int i = tid; i < 196; i += 256) { float v = p[i]; s += v; s2 += v * v; }
    }
    __shared__ float r1[4], r2[4];
    for (int sh = 32; sh; sh >>= 1) { s += __shfl_xor(s, sh); s2 += __shfl_xor(s2, sh); }
    if ((tid & 63) == 0) { r1[tid >> 6] = s; r2[tid >> 6] = s2; }
    __syncthreads();
    if (tid == 0) {
        float S = r1[0] + r1[1] + r1[2] + r1[3];
        float S2 = r2[0] + r2[1] + r2[2] + r2[3];
        float m = S / 6272.f;
        float v = S2 / 6272.f - m * m;
        stats[2 * ch] = m;
        stats[2 * ch + 1] = rsqrtf(v + 1e-5f);
    }
}

__global__ void k_bn_apply_relu(float* __restrict__ y, const float* __restrict__ stats,
                                const float* __restrict__ g, const float* __restrict__ be,
                                int C) {
    int idx = blockIdx.x;           // b*C + ch
    int ch = idx % C;
    int s = threadIdx.x;
    if (s < 196) {
        float m = stats[2 * ch], r = stats[2 * ch + 1];
        float v = y[(size_t)idx * 196 + s];
        y[(size_t)idx * 196 + s] = fmaxf((v - m) * r * g[ch] + be[ch], 0.f);
    }
}

// ---------------- catnum: Linear(A->196) + BN over batch + SiLU -------------
__global__ void k_catnum(const float* __restrict__ inp, int A,
                         const float* __restrict__ w, const float* __restrict__ bias,
                         const float* __restrict__ g, const float* __restrict__ be,
                         float* __restrict__ outv) {
    int j = blockIdx.x;             // feature 0..195
    int lane = threadIdx.x;         // 64 threads, 32 active
    float v = 0.f;
    if (lane < 32) {
        v = bias[j];
        for (int k = 0; k < A; ++k) v += inp[lane * A + k] * w[j * A + k];
    }
    float s = (lane < 32) ? v : 0.f;
    float s2 = (lane < 32) ? v * v : 0.f;
    for (int m = 16; m; m >>= 1) { s += __shfl_xor(s, m, 32); s2 += __shfl_xor(s2, m, 32); }
    if (lane < 32) {
        float mean = s / 32.f;
        float var = s2 / 32.f - mean * mean;
        float rstd = rsqrtf(var + 1e-5f);
        float t = (v - mean) * rstd * g[j] + be[j];
        t = t / (1.f + expf(-t));   // SiLU
        outv[lane * 196 + j] = t;
    }
}

__global__ void k_textbuild(const float* __restrict__ toh, const float* __restrict__ tnm,
                            float* __restrict__ text) {
    int idx = blockIdx.x;           // b*45+c
    int b = idx / 45, c = idx - b * 45;
    int s = threadIdx.x;
    if (s < 196) text[(size_t)idx * 196 + s] = (c < 30) ? toh[b * 196 + s] : tnm[b * 196 + s];
}

// ---------------- GCN ----------------
__global__ void k_gcn_dist(const float* __restrict__ f, float* __restrict__ dist, int C) {
    int idx = blockIdx.x;           // b*C+i
    int b = idx / C;
    __shared__ float fi[196];
    int tid = threadIdx.x;
    for (int n = tid; n < 196; n += blockDim.x) fi[n] = f[(size_t)idx * 196 + n];
    __syncthreads();
    if (tid < C) {
        const float* fj = &f[(size_t)(b * C + tid) * 196];
        float s = 0.f;
        for (int n = 0; n < 196; ++n) s += fabsf(fi[n] - fj[n]);
        dist[(size_t)idx * C + tid] = expf(-s);
    }
}

__global__ void k_gcn_spmm(const float* __restrict__ dist, const float* __restrict__ f,
                           float* __restrict__ tmp, int C) {
    int idx = blockIdx.x;           // b*C+i
    int b = idx / C;
    __shared__ float ds[128];
    for (int j = threadIdx.x; j < C; j += 256) ds[j] = dist[(size_t)idx * C + j];
    __syncthreads();
    int n = threadIdx.x;
    if (n < 196) {
        float acc = 0.f;
        for (int j = 0; j < C; ++j) acc += ds[j] * f[(size_t)(b * C + j) * 196 + n];
        tmp[(size_t)idx * 196 + n] = acc;
    }
}

__global__ void k_gcn_fin(const float* __restrict__ tmp, const float* __restrict__ wt,
                          const float* __restrict__ bias, const float* __restrict__ f,
                          float* __restrict__ out) {
    int row = blockIdx.x;
    __shared__ float ts[196];
    for (int n = threadIdx.x; n < 196; n += 256) ts[n] = tmp[(size_t)row * 196 + n];
    __syncthreads();
    int k = threadIdx.x;
    if (k < 196) {
        float acc = bias[k];
        for (int n = 0; n < 196; ++n) acc += ts[n] * wt[n * 196 + k];
        out[(size_t)row * 196 + k] = fmaxf(acc, 0.f) + f[(size_t)row * 196 + k];
    }
}

// ---------------- LayerNorm over last dim (196), eps 1e-6 ----------------
__global__ void k_ln(const float* __restrict__ x, const float* __restrict__ g,
                     const float* __restrict__ be, float* __restrict__ out) {
    int row = blockIdx.x;
    int lane = threadIdx.x;         // 64
    float v[4]; float s = 0.f, s2 = 0.f;
#pragma unroll
    for (int k = 0; k < 4; ++k) {
        int n = lane + 64 * k;
        v[k] = (n < 196) ? x[(size_t)row * 196 + n] : 0.f;
        s += v[k]; s2 += v[k] * v[k];
    }
    for (int m = 32; m; m >>= 1) { s += __shfl_xor(s, m); s2 += __shfl_xor(s2, m); }
    float mean = s / 196.f;
    float var = s2 / 196.f - mean * mean;
    float rstd = rsqrtf(var + 1e-6f);
#pragma unroll
    for (int k = 0; k < 4; ++k) {
        int n = lane + 64 * k;
        if (n < 196) out[(size_t)row * 196 + n] = (v[k] - mean) * rstd * g[n] + be[n];
    }
}

// ---------------- row GEMV: out = act(x @ wt + b) ----------------
template <int RELU>
__global__ void k_lin(const float* __restrict__ x, const float* __restrict__ wt,
                      const float* __restrict__ bias, float* __restrict__ out) {
    int row = blockIdx.x;
    __shared__ float xs[196];
    for (int n = threadIdx.x; n < 196; n += 256) xs[n] = x[(size_t)row * 196 + n];
    __syncthreads();
    int o = threadIdx.x;
    if (o < 196) {
        float acc = bias[o];
        for (int n = 0; n < 196; ++n) acc += xs[n] * wt[n * 196 + o];
        out[(size_t)row * 196 + o] = RELU ? fmaxf(acc, 0.f) : acc;
    }
}

// out = x1@w1t + b1 + x2@w2t + b2 + res
__global__ void k_fuse2(const float* __restrict__ x1, const float* __restrict__ w1t,
                        const float* __restrict__ b1, const float* __restrict__ x2,
                        const float* __restrict__ w2t, const float* __restrict__ b2,
                        const float* __restrict__ res, float* __restrict__ out) {
    int row = blockIdx.x;
    __shared__ float s1[196], s2[196];
    for (int n = threadIdx.x; n < 196; n += 256) {
        s1[n] = x1[(size_t)row * 196 + n];
        s2[n] = x2[(size_t)row * 196 + n];
    }
    __syncthreads();
    int o = threadIdx.x;
    if (o < 196) {
        float acc = b1[o] + b2[o] + res[(size_t)row * 196 + o];
        for (int n = 0; n < 196; ++n)
            acc += s1[n] * w1t[n * 196 + o] + s2[n] * w2t[n * 196 + o];
        out[(size_t)row * 196 + o] = acc;
    }
}

// ---------------- attention: A = softmax(q @ k^T) ----------------
__global__ void k_att(const float* __restrict__ q, const float* __restrict__ k,
                      float* __restrict__ A, int R2) {
    int i = blockIdx.x, b = blockIdx.y, R1 = gridDim.x;
    __shared__ float qs[196];
    __shared__ float red[2];
    int tid = threadIdx.x;
    for (int n = tid; n < 196; n += blockDim.x) qs[n] = q[(size_t)(b * R1 + i) * 196 + n];
    __syncthreads();
    float sc = -1e30f;
    if (tid < R2) {
        const float* kr = &k[(size_t)(b * R2 + tid) * 196];
        float acc = 0.f;
        for (int n = 0; n < 196; ++n) acc += qs[n] * kr[n];
        sc = acc;
    }
    float m = sc;
    for (int sh = 32; sh; sh >>= 1) m = fmaxf(m, __shfl_xor(m, sh));
    int nw = blockDim.x >> 6;
    if (nw > 1) {
        if ((tid & 63) == 0) red[tid >> 6] = m;
        __syncthreads();
        m = fmaxf(red[0], red[1]);
        __syncthreads();
    }
    float e = (tid < R2) ? expf(sc - m) : 0.f;
    float s = e;
    for (int sh = 32; sh; sh >>= 1) s += __shfl_xor(s, sh);
    if (nw > 1) {
        if ((tid & 63) == 0) red[tid >> 6] = s;
        __syncthreads();
        s = red[0] + red[1];
    }
    if (tid < R2) A[(size_t)(b * R1 + i) * R2 + tid] = e / s;
}

// out[b,i,:] = sum_j A[b,i,j] * v[b,j,:]
__global__ void k_attv(const float* __restrict__ A, const float* __restrict__ v,
                       float* __restrict__ out, int R2) {
    int i = blockIdx.x, b = blockIdx.y, R1 = gridDim.x;
    __shared__ float as[128];
    int tid = threadIdx.x;
    for (int j = tid; j < R2; j += 256) as[j] = A[(size_t)(b * R1 + i) * R2 + j];
    __syncthreads();
    if (tid < 196) {
        float acc = 0.f;
        for (int j = 0; j < R2; ++j) acc += as[j] * v[(size_t)(b * R2 + j) * 196 + tid];
        out[(size_t)(b * R1 + i) * 196 + tid] = acc;
    }
}

// ---------------- feat = concat(ci + c5f, ct + txf) ----------------
__global__ void k_featbuild(const float* __restrict__ ci, const float* __restrict__ c5f,
                            const float* __restrict__ ct, const float* __restrict__ txf,
                            float* __restrict__ feat) {
    int idx = blockIdx.x;           // b*173+c
    int b = idx / 173, c = idx - b * 173;
    int s = threadIdx.x;
    if (s < 196) {
        float v;
        if (c < 128)
            v = ci[(size_t)(b * 128 + c) * 196 + s] + c5f[(size_t)(b * 128 + c) * 196 + s];
        else
            v = ct[(size_t)(b * 45 + c - 128) * 196 + s] + txf[(size_t)(b * 45 + c - 128) * 196 + s];
        feat[(size_t)idx * 196 + s] = v;
    }
}

// ---------------- 1x1x1 conv (channel mix), relu, optional residual --------
template <int RES>
__global__ void k_conv1x1(const float* __restrict__ x, const float* __restrict__ w,
                          const float* __restrict__ bias, const float* __restrict__ res,
                          float* __restrict__ out, int C) {
    int o = blockIdx.x, b = blockIdx.y;
    __shared__ float wsm[173];
    for (int c = threadIdx.x; c < C; c += 256) wsm[c] = w[o * C + c];
    __syncthreads();
    int s = threadIdx.x;
    if (s < 196) {
        float acc = bias[o];
        for (int c = 0; c < C; ++c) acc += wsm[c] * x[(size_t)(b * C + c) * 196 + s];
        acc = fmaxf(acc, 0.f);
        if (RES) acc += res[(size_t)(b * C + o) * 196 + s];
        out[(size_t)(b * C + o) * 196 + s] = acc;
    }
}

// ---------------- CMSA attention over positions ----------------
__global__ void k_cmsa_att(const float* __restrict__ q, float* __restrict__ A) {
    int i = blockIdx.x, b = blockIdx.y;   // i in [0,196)
    __shared__ float col[173];
    __shared__ float red[4];
    int tid = threadIdx.x;
    for (int c = tid; c < 173; c += 256) col[c] = q[(size_t)(b * 173 + c) * 196 + i];
    __syncthreads();
    float sc = -1e30f;
    if (tid < 196) {
        float acc = 0.f;
        for (int c = 0; c < 173; ++c) acc += col[c] * q[(size_t)(b * 173 + c) * 196 + tid];
        sc = acc;
    }
    float m = sc;
    for (int sh = 32; sh; sh >>= 1) m = fmaxf(m, __shfl_xor(m, sh));
    if ((tid & 63) == 0) red[tid >> 6] = m;
    __syncthreads();
    m = fmaxf(fmaxf(red[0], red[1]), fmaxf(red[2], red[3]));
    __syncthreads();
    float e = (tid < 196) ? expf(sc - m) : 0.f;
    float s = e;
    for (int sh = 32; sh; sh >>= 1) s += __shfl_xor(s, sh);
    if ((tid & 63) == 0) red[tid >> 6] = s;
    __syncthreads();
    s = red[0] + red[1] + red[2] + red[3];
    if (tid < 196) A[(size_t)(b * 196 + i) * 196 + tid] = e / s;
}

__global__ void k_cmsa_apply(const float* __restrict__ A, const float* __restrict__ q,
                             float* __restrict__ fea) {
    int c = blockIdx.x, b = blockIdx.y;
    __shared__ float qs[196];
    int tid = threadIdx.x;
    for (int n = tid; n < 196; n += 256) qs[n] = q[(size_t)(b * 173 + c) * 196 + n];
    __syncthreads();
    if (tid < 196) {
        float acc = 0.f;
        const float* Ar = &A[(size_t)(b * 196 + tid) * 196];
        for (int j = 0; j < 196; ++j) acc += Ar[j] * qs[j];
        fea[(size_t)(b * 173 + c) * 196 + tid] = acc;
    }
}

// ---------------- final classifier ----------------
__global__ void k_finale(const float* __restrict__ toh, const float* __restrict__ tnm,
                         const float* __restrict__ cms, const float* __restrict__ cls_w,
                         const float* __restrict__ cls_b, float* __restrict__ out) {
    int b = blockIdx.x;
    __shared__ float pcm[173];
    __shared__ float r1[4], r2[4];
    int tid = threadIdx.x;
    float a = (tid < 196) ? toh[b * 196 + tid] : 0.f;
    float c = (tid < 196) ? tnm[b * 196 + tid] : 0.f;
    for (int sh = 32; sh; sh >>= 1) { a += __shfl_xor(a, sh); c += __shfl_xor(c, sh); }
    if ((tid & 63) == 0) { r1[tid >> 6] = a; r2[tid >> 6] = c; }
    if (tid < 173) {
        float s = 0.f;
        const float* p = &cms[(size_t)(b * 173 + tid) * 196];
        for (int n = 0; n < 196; ++n) s += p[n];
        pcm[tid] = s;
    }
    __syncthreads();
    if (tid < 2) {
        float soh = r1[0] + r1[1] + r1[2] + r1[3];
        float snm = r2[0] + r2[1] + r2[2] + r2[3];
        const float* wrow = &cls_w[tid * 218];
        float acc = cls_b[tid];
        float w1 = 0.f, w2 = 0.f;
        for (int k = 0; k < 30; ++k) w1 += wrow[k];
        for (int k = 30; k < 45; ++k) w2 += wrow[k];
        acc += soh * w1 + snm * w2;
        for (int k = 0; k < 173; ++k) acc += wrow[45 + k] * pcm[k];
        out[b * 2 + tid] = acc;
    }
}

// ---------------------------------------------------------------------------
extern "C" void kernel_launch(void* const* d_in, const int* in_sizes, int n_in,
                              void* d_out, int out_size, void* d_ws, size_t ws_size,
                              hipStream_t stream) {
    const float* x      = (const float*)d_in[0];
    const float* oneHot = (const float*)d_in[1];
    const float* num    = (const float*)d_in[2];
    const float* c1_w1  = (const float*)d_in[3];
    const float* c1_g1  = (const float*)d_in[5];
    const float* c1_be1 = (const float*)d_in[6];
    const float* c1_w2  = (const float*)d_in[7];
    const float* c1_g2  = (const float*)d_in[9];
    const float* c1_be2 = (const float*)d_in[10];
    const float* oh_w   = (const float*)d_in[11];
    const float* oh_b   = (const float*)d_in[12];
    const float* oh_g   = (const float*)d_in[13];
    const float* oh_be  = (const float*)d_in[14];
    const float* nm_w   = (const float*)d_in[15];
    const float* nm_b   = (const float*)d_in[16];
    const float* nm_g   = (const float*)d_in[17];
    const float* nm_be  = (const float*)d_in[18];
    const float* gm1_w  = (const float*)d_in[19];
    const float* gm1_b  = (const float*)d_in[20];
    const float* gm2_w  = (const float*)d_in[21];
    const float* gm2_b  = (const float*)d_in[22];
    const float* ln1_g  = (const float*)d_in[23];
    const float* ln1_b  = (const float*)d_in[24];
    const float* ln2_g  = (const float*)d_in[25];
    const float* ln2_b  = (const float*)d_in[26];
    const float* e1_w   = (const float*)d_in[27];
    const float* e1_b   = (const float*)d_in[28];
    const float* e2_w   = (const float*)d_in[29];
    const float* e2_b   = (const float*)d_in[30];
    const float* f1_w   = (const float*)d_in[31];
    const float* f1_b   = (const float*)d_in[32];
    const float* f2_w   = (const float*)d_in[33];
    const float* f2_b   = (const float*)d_in[34];
    const float* f3_w   = (const float*)d_in[35];
    const float* f3_b   = (const float*)d_in[36];
    const float* f4_w   = (const float*)d_in[37];
    const float* f4_b   = (const float*)d_in[38];
    const float* cm_w   = (const float*)d_in[39];
    const float* cm_b   = (const float*)d_in[40];
    const float* cmf_w  = (const float*)d_in[41];
    const float* cmf_b  = (const float*)d_in[42];
    const float* cls_w  = (const float*)d_in[43];
    const float* cls_b  = (const float*)d_in[44];
    float* out = (float*)d_out;
    float* W = (float*)d_ws;

    // ---- workspace layout (floats) ----
    const size_t L = 802816;   // 32*128*196
    const size_t T = 282240;   // 32*45*196
    const size_t F3 = 1085056; // 32*173*196
    const size_t S2 = 1229312; // 32*196*196
    const size_t o_A = 0;             // conv1 -> h -> gcn tmp1 -> iq -> ci
    const size_t o_B = L;             // conv2 -> conv5(f) -> c5f_ln
    const size_t o_C = 2 * L;         // conv5 post-gcn (c5f)
    const size_t o_L1 = 3 * L;        // img_fea        (also conv partials)
    const size_t o_L2 = 4 * L;        // it_fea
    const size_t o_t1 = 5 * L;        // text(f) -> tq -> ct
    const size_t o_t2 = o_t1 + T;     // gcn2 tmp -> txf_ln
    const size_t o_t3 = o_t2 + T;     // text post-gcn (txf)
    const size_t o_t5 = o_t3 + T;     // text_fea
    const size_t o_t6 = o_t5 + T;     // ti_fea
    const size_t o_d1 = o_t6 + T;     // dist1 / att_ii  (32*128*128)
    const size_t o_ait = o_d1 + 524288;   // att_it (32*128*45)
    const size_t o_ati = o_ait + 184320;  // att_ti (32*45*128)
    const size_t o_d2 = o_ati + 184320;   // dist2 / att_tt (32*45*45)
    const size_t o_toh = o_d2 + 64800;
    const size_t o_tnm = o_toh + 6272;
    const size_t o_st = o_tnm + 6272;     // bn stats
    const size_t o_wT = o_st + 1024;      // 8 transposed 196x196
    const size_t o_feat = o_wT + 8 * 38416;
    const size_t o_q = o_feat + F3;       // q_cmsa, later cmsa_out
    const size_t o_Acm = o_q + F3;        // [32,196,196]
    const size_t o_fea = o_Acm + S2;      // cmsa fea
    // total ~44.8 MB; conv partials [3L, 11L) overlap post-conv-only buffers

    float* part = W + o_L1;               // 8*L floats of partials
    float* gm1T = W + o_wT + 0 * 38416;
    float* gm2T = W + o_wT + 1 * 38416;
    float* e1T  = W + o_wT + 2 * 38416;
    float* e2T  = W + o_wT + 3 * 38416;
    float* f1T  = W + o_wT + 4 * 38416;
    float* f2T  = W + o_wT + 5 * 38416;
    float* f3T  = W + o_wT + 6 * 38416;
    float* f4T  = W + o_wT + 7 * 38416;

    // ---- conv1 + reduce + BN + relu -> A ----
    k_conv3d_v2<<<dim3(4, 8, 32), 256, 0, stream>>>(x, c1_w1, part, 320, 40, 128);
    k_reduce_part<<<3136, 256, 0, stream>>>(part, W + o_A, 802816);
    k_bn_stats<<<128, 256, 0, stream>>>(W + o_A, W + o_st, 128);
    k_bn_apply_relu<<<4096, 256, 0, stream>>>(W + o_A, W + o_st, c1_g1, c1_be1, 128);

    // ---- conv2 + reduce + BN + relu -> conv5(f) in B ----
    k_conv3d_v2<<<dim3(4, 8, 32), 256, 0, stream>>>(W + o_A, c1_w2, part, 128, 16, 128);
    k_reduce_part<<<3136, 256, 0, stream>>>(part, W + o_B, 802816);
    k_bn_stats<<<128, 256, 0, stream>>>(W + o_B, W + o_st + 512, 128);
    k_bn_apply_relu<<<4096, 256, 0, stream>>>(W + o_B, W + o_st + 512, c1_g2, c1_be2, 128);

    // ---- weight transposes (AFTER convs: partials overlap o_wT) ----
    P8 p8;
    p8.p[0] = gm1_w; p8.p[1] = gm2_w; p8.p[2] = e1_w; p8.p[3] = e2_w;
    p8.p[4] = f1_w;  p8.p[5] = f2_w;  p8.p[6] = f3_w; p8.p[7] = f4_w;
    k_transpose8<<<dim3(196, 8), 256, 0, stream>>>(p8, W + o_wT);

    // ---- catnum (oneHot / num) ----
    k_catnum<<<196, 64, 0, stream>>>(oneHot, 24, oh_w, oh_b, oh_g, oh_be, W + o_toh);
    k_catnum<<<196, 64, 0, stream>>>(num, 11, nm_w, nm_b, nm_g, nm_be, W + o_tnm);
    k_textbuild<<<32 * 45, 256, 0, stream>>>(W + o_toh, W + o_tnm, W + o_t1);

    // ---- GCN on conv5 (C=128): f=B, tmp=A, out=C ----
    k_gcn_dist<<<4096, 128, 0, stream>>>(W + o_B, W + o_d1, 128);
    k_gcn_spmm<<<4096, 256, 0, stream>>>(W + o_d1, W + o_B, W + o_A, 128);
    k_gcn_fin<<<4096, 256, 0, stream>>>(W + o_A, gm1T, gm1_b, W + o_B, W + o_C);

    // ---- GCN on text (C=45): f=t1, tmp=t2, out=t3 ----
    k_gcn_dist<<<1440, 64, 0, stream>>>(W + o_t1, W + o_d2, 45);
    k_gcn_spmm<<<1440, 256, 0, stream>>>(W + o_d2, W + o_t1, W + o_t2, 45);
    k_gcn_fin<<<1440, 256, 0, stream>>>(W + o_t2, gm2T, gm2_b, W + o_t1, W + o_t3);

    // ---- LayerNorms: c5f_ln -> B, txf_ln -> t2 ----
    k_ln<<<4096, 64, 0, stream>>>(W + o_C, ln1_g, ln1_b, W + o_B);
    k_ln<<<1440, 64, 0, stream>>>(W + o_t3, ln2_g, ln2_b, W + o_t2);

    // ---- iq -> A, tq -> t1 ----
    k_lin<1><<<4096, 256, 0, stream>>>(W + o_B, e1T, e1_b, W + o_A);
    k_lin<1><<<1440, 256, 0, stream>>>(W + o_t2, e2T, e2_b, W + o_t1);

    // ---- attention matrices ----
    k_att<<<dim3(128, 32), 128, 0, stream>>>(W + o_A, W + o_A, W + o_d1, 128);  // att_ii
    k_att<<<dim3(45, 32), 64, 0, stream>>>(W + o_t1, W + o_t1, W + o_d2, 45);   // att_tt
    k_att<<<dim3(128, 32), 64, 0, stream>>>(W + o_A, W + o_t1, W + o_ait, 45);  // att_it
    k_att<<<dim3(45, 32), 128, 0, stream>>>(W + o_t1, W + o_A, W + o_ati, 128); // att_ti

    // ---- attention-weighted values ----
    k_attv<<<dim3(128, 32), 256, 0, stream>>>(W + o_d1, W + o_A, W + o_L1, 128);  // img_fea
    k_attv<<<dim3(45, 32), 256, 0, stream>>>(W + o_d2, W + o_t1, W + o_t5, 45);   // text_fea
    k_attv<<<dim3(128, 32), 256, 0, stream>>>(W + o_ait, W + o_t1, W + o_L2, 45); // it_fea
    k_attv<<<dim3(45, 32), 256, 0, stream>>>(W + o_ati, W + o_A, W + o_t6, 128);  // ti_fea

    // ---- ci -> A, ct -> t1 ----
    k_fuse2<<<4096, 256, 0, stream>>>(W + o_L1, f1T, f1_b, W + o_L2, f3T, f3_b,
                                      W + o_B, W + o_A);
    k_fuse2<<<1440, 256, 0, stream>>>(W + o_t5, f2T, f2_b, W + o_t6, f4T, f4_b,
                                      W + o_t2, W + o_t1);

    // ---- feat ----
    k_featbuild<<<32 * 173, 256, 0, stream>>>(W + o_A, W + o_C, W + o_t1, W + o_t3,
                                              W + o_feat);

    // ---- CMSA ----
    k_conv1x1<0><<<dim3(173, 32), 256, 0, stream>>>(W + o_feat, cm_w, cm_b, nullptr,
                                                    W + o_q, 173);
    k_cmsa_att<<<dim3(196, 32), 256, 0, stream>>>(W + o_q, W + o_Acm);
    k_cmsa_apply<<<dim3(173, 32), 256, 0, stream>>>(W + o_Acm, W + o_q, W + o_fea);
    k_conv1x1<1><<<dim3(173, 32), 256, 0, stream>>>(W + o_fea, cmf_w, cmf_b, W + o_feat,
                                                    W + o_q, 173);

    // ---- final classifier ----
    k_finale<<<32, 256, 0, stream>>>(W + o_toh, W + o_tnm, W + o_q, cls_w, cls_b, out);
}